// Round 1
// baseline (368.801 us; speedup 1.0000x reference)
//
#include <hip/hip_runtime.h>
#include <hip/hip_bf16.h>
#include <stdint.h>

// Problem constants
#define MPTS  524288      // M per batch
#define NB    2           // N
#define CCH   80          // C
#define HWDIM 64          // H = W
#define HID   64

typedef __bf16 bf16x8 __attribute__((ext_vector_type(8)));
typedef float  f32x4  __attribute__((ext_vector_type(4)));

union ABFrag { uint4 q; bf16x8 v; unsigned short s[8]; };

__device__ __forceinline__ unsigned short f2bf(float f) {
    union { float f; unsigned u; } v; v.f = f;
    unsigned u = v.u;
    return (unsigned short)((u + 0x7FFFu + ((u >> 16) & 1u)) >> 16);
}

// ---------------------------------------------------------------------------
// Pre-kernel 1: planes [N,P,C,H,W] f32  ->  planesT [N*P, H, W, C] f32
// One block per (np, y). LDS tile transpose, stride 65 to kill bank conflicts.
__global__ void transpose_planes(const float* __restrict__ planes,
                                 float* __restrict__ planesT) {
    __shared__ float tile[CCH * 65];
    int b  = blockIdx.x;            // np*64 + y
    int np = b >> 6, y = b & 63;
    int t  = threadIdx.x;
    const float* src = planes + (size_t)np * CCH * HWDIM * HWDIM + (size_t)y * HWDIM;
    for (int i = t; i < CCH * HWDIM; i += 256) {
        int c = i >> 6, w = i & 63;
        tile[c * 65 + w] = src[(size_t)c * (HWDIM * HWDIM) + w];
    }
    __syncthreads();
    float* dst = planesT + ((size_t)np * HWDIM + y) * HWDIM * CCH;
    for (int i = t; i < CCH * HWDIM; i += 256) {
        int w = i / CCH, c = i - w * CCH;
        dst[i] = tile[c * 65 + w];
    }
}

// ---------------------------------------------------------------------------
// Pre-kernel 2: pack W1 (240x64, K-pad to 256), W2, W3 (64x64) into bf16
// MFMA B-fragment order: elem((kk,nt,lane,j)) = W[kk*32 + 8*(lane>>4)+j][nt*16 + (lane&15)]
// wpack ushort layout: W1[0..16384) W2[16384..20480) W3[20480..24576)
__global__ void pack_weights(const float* __restrict__ W1,
                             const float* __restrict__ W2,
                             const float* __restrict__ W3,
                             unsigned short* __restrict__ wpack) {
    int e = blockIdx.x * 256 + threadIdx.x;   // 0..24575
    const float* W; int K; int q;
    if (e < 16384)      { W = W1; K = 240; q = e; }
    else if (e < 20480) { W = W2; K = 64;  q = e - 16384; }
    else                { W = W3; K = 64;  q = e - 20480; }
    int j  = q & 7;
    int l  = (q >> 3) & 63;
    int nt = (q >> 9) & 3;
    int kk = q >> 11;
    int k  = kk * 32 + ((l >> 4) << 3) + j;
    int nn = nt * 16 + (l & 15);
    float v = (k < K) ? W[k * HID + nn] : 0.0f;
    wpack[e] = f2bf(v);
}

// ---------------------------------------------------------------------------
// Main fused kernel: 256 threads = 4 waves, 16 points per wave, 64 per block.
__global__ __launch_bounds__(256) void fused_kernel(
        const float* __restrict__ planesT,
        const float* __restrict__ coords,
        const unsigned short* __restrict__ wpack,
        const float* __restrict__ b1, const float* __restrict__ b2,
        const float* __restrict__ b3, const float* __restrict__ W4,
        const float* __restrict__ b4, float* __restrict__ out) {

    __shared__ __align__(16) unsigned short sW[24576];      // 48 KiB packed weights
    __shared__ __align__(16) unsigned short sH[4 * 16 * 72]; // per-wave H tiles

    int t = threadIdx.x;
    // Stage packed weights block-wide (overlaps with sampling below).
    {
        const uint4* g = (const uint4*)wpack;
        uint4* s = (uint4*)sW;
        #pragma unroll
        for (int i = 0; i < 12; ++i) s[t + i * 256] = g[t + i * 256];
    }

    int wave = t >> 6, lane = t & 63;
    int row  = lane & 15;       // A-row / point-in-wave for sampling
    int kgrp = lane >> 4;       // 0..3 (K-block group)
    int ptbase = blockIdx.x * 64 + wave * 16;
    int mypt   = ptbase + row;              // global point this lane samples
    int n      = mypt >> 19;                // MPTS = 2^19

    const float* cp = coords + (size_t)mypt * 3;
    float c0 = cp[0], c1 = cp[1], c2 = cp[2];

    // -------- Sample 8 A-fragments: lane holds x[row][kk*32 + kgrp*8 .. +8) --
    bf16x8 afr[8];
    #pragma unroll
    for (int kk = 0; kk < 8; ++kk) {
        int k0 = kk * 32 + kgrp * 8;
        if (k0 >= 240) {                    // K padding 240..255
            ABFrag z; z.q = uint4{0, 0, 0, 0};
            afr[kk] = z.v;
            continue;
        }
        int p  = (k0 >= 160) ? 2 : (k0 >= 80 ? 1 : 0);
        int c8 = k0 - p * 80;
        // plane grids: p0:(x,y)  p1:(x,z)  p2:(z,y)
        float gx = (p == 2) ? c2 : c0;
        float gy = (p == 1) ? c2 : c1;
        float fx = (gx + 1.0f) * 32.0f - 0.5f;
        float fy = (gy + 1.0f) * 32.0f - 0.5f;
        float xf = floorf(fx), yf = floorf(fy);
        float wx = fx - xf,    wy = fy - yf;
        int x0 = (int)xf, y0 = (int)yf;
        int x1 = x0 + 1,  y1 = y0 + 1;
        float vx0 = (x0 >= 0 && x0 < 64) ? 1.0f : 0.0f;
        float vx1 = (x1 >= 0 && x1 < 64) ? 1.0f : 0.0f;
        float vy0 = (y0 >= 0 && y0 < 64) ? 1.0f : 0.0f;
        float vy1 = (y1 >= 0 && y1 < 64) ? 1.0f : 0.0f;
        int cx0 = min(max(x0, 0), 63), cx1 = min(max(x1, 0), 63);
        int cy0 = min(max(y0, 0), 63), cy1 = min(max(y1, 0), 63);

        const float* base = planesT + (size_t)(n * 3 + p) * (HWDIM * HWDIM * CCH) + c8;
        float v00[8], v01[8], v10[8], v11[8];
        auto ldc = [&](int yy, int xx, float* o) {
            const float4* q = (const float4*)(base + ((yy << 6) + xx) * CCH);
            float4 a = q[0], bq = q[1];
            o[0] = a.x;  o[1] = a.y;  o[2] = a.z;  o[3] = a.w;
            o[4] = bq.x; o[5] = bq.y; o[6] = bq.z; o[7] = bq.w;
        };
        ldc(cy0, cx0, v00); ldc(cy0, cx1, v01);
        ldc(cy1, cx0, v10); ldc(cy1, cx1, v11);

        float w00 = (1.0f - wx) * (1.0f - wy) * vx0 * vy0;
        float w01 = wx * (1.0f - wy) * vx1 * vy0;
        float w10 = (1.0f - wx) * wy * vx0 * vy1;
        float w11 = wx * wy * vx1 * vy1;

        ABFrag u;
        #pragma unroll
        for (int j = 0; j < 8; ++j) {
            float f = v00[j] * w00 + v01[j] * w01 + v10[j] * w10 + v11[j] * w11;
            u.s[j] = f2bf(f);
        }
        afr[kk] = u.v;
    }

    __syncthreads();   // weights staged

    unsigned short* hw = sH + wave * (16 * 72);

    // -------- Layer 1: K=256(padded), N=64 --------
    f32x4 acc[4] = {{0,0,0,0},{0,0,0,0},{0,0,0,0},{0,0,0,0}};
    #pragma unroll
    for (int kk = 0; kk < 8; ++kk) {
        #pragma unroll
        for (int nt = 0; nt < 4; ++nt) {
            ABFrag bu;
            bu.q = *(const uint4*)(sW + (((kk * 4 + nt) * 64 + lane) << 3));
            acc[nt] = __builtin_amdgcn_mfma_f32_16x16x32_bf16(afr[kk], bu.v, acc[nt], 0, 0, 0);
        }
    }
    #pragma unroll
    for (int nt = 0; nt < 4; ++nt) {
        float bb = b1[nt * 16 + row];
        #pragma unroll
        for (int r = 0; r < 4; ++r) {
            float h = fmaxf(acc[nt][r] + bb, 0.0f);
            hw[(kgrp * 4 + r) * 72 + nt * 16 + row] = f2bf(h);
        }
    }
    __syncthreads();

    // -------- Layer 2: K=64, N=64 --------
    f32x4 acc2[4] = {{0,0,0,0},{0,0,0,0},{0,0,0,0},{0,0,0,0}};
    #pragma unroll
    for (int kk = 0; kk < 2; ++kk) {
        ABFrag au;
        au.q = *(const uint4*)(hw + row * 72 + kk * 32 + kgrp * 8);
        #pragma unroll
        for (int nt = 0; nt < 4; ++nt) {
            ABFrag bu;
            bu.q = *(const uint4*)(sW + (((32 + kk * 4 + nt) * 64 + lane) << 3));
            acc2[nt] = __builtin_amdgcn_mfma_f32_16x16x32_bf16(au.v, bu.v, acc2[nt], 0, 0, 0);
        }
    }
    __syncthreads();
    #pragma unroll
    for (int nt = 0; nt < 4; ++nt) {
        float bb = b2[nt * 16 + row];
        #pragma unroll
        for (int r = 0; r < 4; ++r) {
            float h = fmaxf(acc2[nt][r] + bb, 0.0f);
            hw[(kgrp * 4 + r) * 72 + nt * 16 + row] = f2bf(h);
        }
    }
    __syncthreads();

    // -------- Layer 3: K=64, N=64 (keep result in registers) --------
    f32x4 acc3[4] = {{0,0,0,0},{0,0,0,0},{0,0,0,0},{0,0,0,0}};
    #pragma unroll
    for (int kk = 0; kk < 2; ++kk) {
        ABFrag au;
        au.q = *(const uint4*)(hw + row * 72 + kk * 32 + kgrp * 8);
        #pragma unroll
        for (int nt = 0; nt < 4; ++nt) {
            ABFrag bu;
            bu.q = *(const uint4*)(sW + (((40 + kk * 4 + nt) * 64 + lane) << 3));
            acc3[nt] = __builtin_amdgcn_mfma_f32_16x16x32_bf16(au.v, bu.v, acc3[nt], 0, 0, 0);
        }
    }

    // -------- Layer 4: 64 -> 1, fp32 VALU + 16-lane reduce --------
    float part[4] = {0.f, 0.f, 0.f, 0.f};
    #pragma unroll
    for (int nt = 0; nt < 4; ++nt) {
        float bb  = b3[nt * 16 + row];
        float w4v = W4[nt * 16 + row];
        #pragma unroll
        for (int r = 0; r < 4; ++r) {
            float h = fmaxf(acc3[nt][r] + bb, 0.0f);
            part[r] += h * w4v;
        }
    }
    #pragma unroll
    for (int r = 0; r < 4; ++r) {
        #pragma unroll
        for (int off = 1; off < 16; off <<= 1)
            part[r] += __shfl_xor(part[r], off);
    }
    if (row == 0) {
        float bias4 = b4[0];
        float4 o;
        o.x = part[0] + bias4; o.y = part[1] + bias4;
        o.z = part[2] + bias4; o.w = part[3] + bias4;
        *(float4*)(out + ptbase + kgrp * 4) = o;   // points m = kgrp*4 + r
    }
}

// ---------------------------------------------------------------------------
extern "C" void kernel_launch(void* const* d_in, const int* in_sizes, int n_in,
                              void* d_out, int out_size, void* d_ws, size_t ws_size,
                              hipStream_t stream) {
    const float* planes = (const float*)d_in[0];
    const float* coords = (const float*)d_in[1];
    const float* W1 = (const float*)d_in[2];
    const float* b1 = (const float*)d_in[3];
    const float* W2 = (const float*)d_in[4];
    const float* b2 = (const float*)d_in[5];
    const float* W3 = (const float*)d_in[6];
    const float* b3 = (const float*)d_in[7];
    const float* W4 = (const float*)d_in[8];
    const float* b4 = (const float*)d_in[9];
    float* out = (float*)d_out;

    // Workspace layout: planesT f32 (7,864,320 B) | wpack bf16 (49,152 B)
    float* planesT = (float*)d_ws;
    unsigned short* wpack = (unsigned short*)((char*)d_ws + 7864320);

    hipLaunchKernelGGL(transpose_planes, dim3(NB * 3 * HWDIM), dim3(256), 0, stream,
                       planes, planesT);
    hipLaunchKernelGGL(pack_weights, dim3(96), dim3(256), 0, stream,
                       W1, W2, W3, wpack);

    int nblocks = (NB * MPTS) / 64;   // 16384
    hipLaunchKernelGGL(fused_kernel, dim3(nblocks), dim3(256), 0, stream,
                       planesT, coords, wpack, b1, b2, b3, W4, b4, out);
}

// Round 3
// 249.660 us; speedup vs baseline: 1.4772x; 1.4772x over previous
//
#include <hip/hip_runtime.h>
#include <hip/hip_bf16.h>
#include <stdint.h>

// Problem constants
#define MPTS  524288      // M per batch
#define NB    2           // N
#define CCH   80          // C
#define HWDIM 64          // H = W
#define HID   64

typedef __bf16 bf16x8 __attribute__((ext_vector_type(8)));
typedef float  f32x4  __attribute__((ext_vector_type(4)));

union ABFrag  { uint4 q; bf16x8 v; unsigned short s[8]; };
union CornerH { uint4 q; _Float16 h[8]; };

__device__ __forceinline__ unsigned short f2bf(float f) {
    union { float f; unsigned u; } v; v.f = f;
    unsigned u = v.u;
    return (unsigned short)((u + 0x7FFFu + ((u >> 16) & 1u)) >> 16);
}

// ---------------------------------------------------------------------------
// Pre-kernel 1: planes [N,P,C,H,W] f32  ->  planesT [N*P, H, W, C] fp16
__global__ void transpose_planes(const float* __restrict__ planes,
                                 unsigned short* __restrict__ planesT) {
    __shared__ float tile[CCH * 65];
    int b  = blockIdx.x;            // np*64 + y
    int np = b >> 6, y = b & 63;
    int t  = threadIdx.x;
    const float* src = planes + (size_t)np * CCH * HWDIM * HWDIM + (size_t)y * HWDIM;
    for (int i = t; i < CCH * HWDIM; i += 256) {
        int c = i >> 6, w = i & 63;
        tile[c * 65 + w] = src[(size_t)c * (HWDIM * HWDIM) + w];
    }
    __syncthreads();
    unsigned short* dst = planesT + ((size_t)np * HWDIM + y) * HWDIM * CCH;
    for (int i = t; i < CCH * HWDIM; i += 256) {
        int w = i / CCH, c = i - w * CCH;
        union { _Float16 h; unsigned short u; } cv;
        cv.h = (_Float16)tile[c * 65 + w];
        dst[i] = cv.u;
    }
}

// ---------------------------------------------------------------------------
// Pre-kernel 2 (EXACT round-1 proven layout):
// W1 (240x64, K zero-padded to 256), W2, W3 (64x64) in bf16 MFMA B-fragment
// order: elem((kb,nt,lane,j)) = W[kb*32 + 8*(lane>>4)+j][nt*16 + (lane&15)]
// wpack ushort layout: W1[0..16384) W2[16384..20480) W3[20480..24576)
__global__ void pack_weights(const float* __restrict__ W1,
                             const float* __restrict__ W2,
                             const float* __restrict__ W3,
                             unsigned short* __restrict__ wpack) {
    int e = blockIdx.x * 256 + threadIdx.x;   // 0..24575
    const float* W; int K; int q;
    if (e < 16384)      { W = W1; K = 240; q = e; }
    else if (e < 20480) { W = W2; K = 64;  q = e - 16384; }
    else                { W = W3; K = 64;  q = e - 20480; }
    int j  = q & 7;
    int l  = (q >> 3) & 63;
    int nt = (q >> 9) & 3;
    int kb = q >> 11;
    int k  = kb * 32 + ((l >> 4) << 3) + j;
    int nn = nt * 16 + (l & 15);
    float v = (k < K) ? W[k * HID + nn] : 0.0f;
    wpack[e] = f2bf(v);
}

// ---------------------------------------------------------------------------
// Main fused kernel: 256 threads = 4 waves, 16 points per wave.
// LDS: W1 fragments 32 KB + H tiles 9 KB = 41 KB -> 3 blocks/CU.
__global__ __launch_bounds__(256, 3) void fused_kernel(
        const unsigned short* __restrict__ planesT,
        const float* __restrict__ coords,
        const unsigned short* __restrict__ wpack,
        const float* __restrict__ b1, const float* __restrict__ b2,
        const float* __restrict__ b3, const float* __restrict__ W4,
        const float* __restrict__ b4, float* __restrict__ out) {

    __shared__ __align__(16) unsigned short sW1[16384];      // 32 KiB (K=256 padded)
    __shared__ __align__(16) unsigned short sH[4 * 16 * 72]; // per-wave H tiles

    int t = threadIdx.x;
    {   // Stage W1 fragments: 2048 uint4 over 256 threads.
        const uint4* g = (const uint4*)wpack;
        uint4* s = (uint4*)sW1;
        #pragma unroll
        for (int i = 0; i < 8; ++i) s[t + i * 256] = g[t + i * 256];
    }

    int wave = t >> 6, lane = t & 63;
    int row  = lane & 15;       // point-in-wave (MFMA A row / C col)
    int kgrp = lane >> 4;       // K-group 0..3
    int ptbase = blockIdx.x * 64 + wave * 16;
    int mypt   = ptbase + row;
    int n      = mypt >> 19;    // MPTS = 2^19

    const float* cp = coords + (size_t)mypt * 3;
    float c0 = cp[0], c1 = cp[1], c2 = cp[2];

    // Per-plane bilinear params -> NAMED scalars (no runtime-indexed arrays).
    float w00_0, w01_0, w10_0, w11_0, w00_1, w01_1, w10_1, w11_1,
          w00_2, w01_2, w10_2, w11_2;
    int   o00_0, o01_0, o10_0, o11_0, o00_1, o01_1, o10_1, o11_1,
          o00_2, o01_2, o10_2, o11_2;
    {
        auto setup = [&](float gx, float gy, int pbase,
                         float& w00, float& w01, float& w10, float& w11,
                         int& o00, int& o01, int& o10, int& o11) {
            float fx = (gx + 1.0f) * 32.0f - 0.5f;
            float fy = (gy + 1.0f) * 32.0f - 0.5f;
            float xf = floorf(fx), yf = floorf(fy);
            float wx = fx - xf,    wy = fy - yf;
            int x0 = (int)xf, y0 = (int)yf, x1 = x0 + 1, y1 = y0 + 1;
            float vx0 = (x0 >= 0 && x0 < 64) ? 1.0f : 0.0f;
            float vx1 = (x1 >= 0 && x1 < 64) ? 1.0f : 0.0f;
            float vy0 = (y0 >= 0 && y0 < 64) ? 1.0f : 0.0f;
            float vy1 = (y1 >= 0 && y1 < 64) ? 1.0f : 0.0f;
            int cx0 = min(max(x0, 0), 63), cx1 = min(max(x1, 0), 63);
            int cy0 = min(max(y0, 0), 63), cy1 = min(max(y1, 0), 63);
            w00 = (1.0f - wx) * (1.0f - wy) * vx0 * vy0;
            w01 = wx * (1.0f - wy) * vx1 * vy0;
            w10 = (1.0f - wx) * wy * vx0 * vy1;
            w11 = wx * wy * vx1 * vy1;
            o00 = pbase + ((cy0 << 6) + cx0) * CCH;
            o01 = pbase + ((cy0 << 6) + cx1) * CCH;
            o10 = pbase + ((cy1 << 6) + cx0) * CCH;
            o11 = pbase + ((cy1 << 6) + cx1) * CCH;
        };
        int nb = n * 3 * (HWDIM * HWDIM * CCH);
        setup(c0, c1, nb,                      w00_0, w01_0, w10_0, w11_0,
                                               o00_0, o01_0, o10_0, o11_0);
        setup(c0, c2, nb + HWDIM * HWDIM * CCH, w00_1, w01_1, w10_1, w11_1,
                                               o00_1, o01_1, o10_1, o11_1);
        setup(c2, c1, nb + 2 * HWDIM * HWDIM * CCH, w00_2, w01_2, w10_2, w11_2,
                                               o00_2, o01_2, o10_2, o11_2);
    }

    // -------- Sample 8 A-fragments (lane: x[row][kk*32 + kgrp*8 .. +8)) ----
    ABFrag afr[8];
    #pragma unroll
    for (int kk = 0; kk < 8; ++kk) {
        int k0 = kk * 32 + kgrp * 8;
        if (k0 >= 240) {                    // K padding 240..255
            afr[kk].q.x = afr[kk].q.y = afr[kk].q.z = afr[kk].q.w = 0u;
            continue;
        }
        bool g2 = (k0 >= 160);
        bool g1 = (k0 >= 80) && !g2;
        int c8 = k0 - (g2 ? 160 : (g1 ? 80 : 0));
        int o00 = g2 ? o00_2 : (g1 ? o00_1 : o00_0);
        int o01 = g2 ? o01_2 : (g1 ? o01_1 : o01_0);
        int o10 = g2 ? o10_2 : (g1 ? o10_1 : o10_0);
        int o11 = g2 ? o11_2 : (g1 ? o11_1 : o11_0);
        float a00 = g2 ? w00_2 : (g1 ? w00_1 : w00_0);
        float a01 = g2 ? w01_2 : (g1 ? w01_1 : w01_0);
        float a10 = g2 ? w10_2 : (g1 ? w10_1 : w10_0);
        float a11 = g2 ? w11_2 : (g1 ? w11_1 : w11_0);

        CornerH u00, u01, u10, u11;
        u00.q = *(const uint4*)(planesT + o00 + c8);
        u01.q = *(const uint4*)(planesT + o01 + c8);
        u10.q = *(const uint4*)(planesT + o10 + c8);
        u11.q = *(const uint4*)(planesT + o11 + c8);
        #pragma unroll
        for (int j = 0; j < 8; ++j) {
            float f = a00 * (float)u00.h[j] + a01 * (float)u01.h[j]
                    + a10 * (float)u10.h[j] + a11 * (float)u11.h[j];
            afr[kk].s[j] = f2bf(f);
        }
    }

    __syncthreads();   // W1 staged

    // -------- Layer 1: K=256(padded), N=64, B from LDS ---------------------
    f32x4 acc[4] = {{0,0,0,0},{0,0,0,0},{0,0,0,0},{0,0,0,0}};
    #pragma unroll
    for (int kk = 0; kk < 8; ++kk) {
        #pragma unroll
        for (int nt = 0; nt < 4; ++nt) {
            ABFrag bu;
            bu.q = *(const uint4*)(sW1 + (kk * 4 + nt) * 512 + lane * 8);
            acc[nt] = __builtin_amdgcn_mfma_f32_16x16x32_bf16(afr[kk].v, bu.v, acc[nt], 0, 0, 0);
        }
    }

    unsigned short* hw = sH + wave * (16 * 72);

    // Epilogue 1
    #pragma unroll
    for (int nt = 0; nt < 4; ++nt) {
        float bb = b1[nt * 16 + row];
        #pragma unroll
        for (int r = 0; r < 4; ++r) {
            float h = fmaxf(acc[nt][r] + bb, 0.0f);
            hw[(kgrp * 4 + r) * 72 + nt * 16 + row] = f2bf(h);
        }
    }
    __syncthreads();

    // -------- Layer 2: K=64, B fragments from global (L1-hot) --------------
    f32x4 acc2[4] = {{0,0,0,0},{0,0,0,0},{0,0,0,0},{0,0,0,0}};
    #pragma unroll
    for (int kk = 0; kk < 2; ++kk) {
        ABFrag au;
        au.q = *(const uint4*)(hw + row * 72 + kk * 32 + kgrp * 8);
        #pragma unroll
        for (int nt = 0; nt < 4; ++nt) {
            ABFrag bu;
            bu.q = *(const uint4*)(wpack + 16384 + (kk * 4 + nt) * 512 + lane * 8);
            acc2[nt] = __builtin_amdgcn_mfma_f32_16x16x32_bf16(au.v, bu.v, acc2[nt], 0, 0, 0);
        }
    }
    __syncthreads();

    // Epilogue 2
    #pragma unroll
    for (int nt = 0; nt < 4; ++nt) {
        float bb = b2[nt * 16 + row];
        #pragma unroll
        for (int r = 0; r < 4; ++r) {
            float h = fmaxf(acc2[nt][r] + bb, 0.0f);
            hw[(kgrp * 4 + r) * 72 + nt * 16 + row] = f2bf(h);
        }
    }
    __syncthreads();

    // -------- Layer 3: K=64, B from global ---------------------------------
    f32x4 acc3[4] = {{0,0,0,0},{0,0,0,0},{0,0,0,0},{0,0,0,0}};
    #pragma unroll
    for (int kk = 0; kk < 2; ++kk) {
        ABFrag au;
        au.q = *(const uint4*)(hw + row * 72 + kk * 32 + kgrp * 8);
        #pragma unroll
        for (int nt = 0; nt < 4; ++nt) {
            ABFrag bu;
            bu.q = *(const uint4*)(wpack + 20480 + (kk * 4 + nt) * 512 + lane * 8);
            acc3[nt] = __builtin_amdgcn_mfma_f32_16x16x32_bf16(au.v, bu.v, acc3[nt], 0, 0, 0);
        }
    }

    // -------- Layer 4: 64 -> 1, fp32 VALU + 16-lane reduce -----------------
    float part[4] = {0.f, 0.f, 0.f, 0.f};
    #pragma unroll
    for (int nt = 0; nt < 4; ++nt) {
        float bb  = b3[nt * 16 + row];
        float w4v = W4[nt * 16 + row];
        #pragma unroll
        for (int r = 0; r < 4; ++r) {
            float h = fmaxf(acc3[nt][r] + bb, 0.0f);
            part[r] += h * w4v;
        }
    }
    #pragma unroll
    for (int r = 0; r < 4; ++r) {
        #pragma unroll
        for (int off = 1; off < 16; off <<= 1)
            part[r] += __shfl_xor(part[r], off);
    }
    if (row == 0) {
        float bias4 = b4[0];
        float4 o;
        o.x = part[0] + bias4; o.y = part[1] + bias4;
        o.z = part[2] + bias4; o.w = part[3] + bias4;
        *(float4*)(out + ptbase + kgrp * 4) = o;   // points m = kgrp*4 + r
    }
}

// ---------------------------------------------------------------------------
extern "C" void kernel_launch(void* const* d_in, const int* in_sizes, int n_in,
                              void* d_out, int out_size, void* d_ws, size_t ws_size,
                              hipStream_t stream) {
    const float* planes = (const float*)d_in[0];
    const float* coords = (const float*)d_in[1];
    const float* W1 = (const float*)d_in[2];
    const float* b1 = (const float*)d_in[3];
    const float* W2 = (const float*)d_in[4];
    const float* b2 = (const float*)d_in[5];
    const float* W3 = (const float*)d_in[6];
    const float* b3 = (const float*)d_in[7];
    const float* W4 = (const float*)d_in[8];
    const float* b4 = (const float*)d_in[9];
    float* out = (float*)d_out;

    // Workspace: planesT fp16 (3,932,160 B) | wpack bf16 (49,152 B)
    unsigned short* planesT = (unsigned short*)d_ws;
    unsigned short* wpack   = (unsigned short*)((char*)d_ws + 3932160);

    hipLaunchKernelGGL(transpose_planes, dim3(NB * 3 * HWDIM), dim3(256), 0, stream,
                       planes, planesT);
    hipLaunchKernelGGL(pack_weights, dim3(96), dim3(256), 0, stream,
                       W1, W2, W3, wpack);

    int nblocks = (NB * MPTS) / 64;   // 16384
    hipLaunchKernelGGL(fused_kernel, dim3(nblocks), dim3(256), 0, stream,
                       planesT, coords, wpack, b1, b2, b3, W4, b4, out);
}

// Round 4
// 227.668 us; speedup vs baseline: 1.6199x; 1.0966x over previous
//
#include <hip/hip_runtime.h>
#include <hip/hip_bf16.h>
#include <stdint.h>

// Problem constants
#define MPTS  524288      // M per batch
#define NB    2           // N
#define CCH   80          // C
#define HWDIM 64          // H = W
#define HID   64

typedef _Float16 f16x2 __attribute__((ext_vector_type(2)));
typedef _Float16 f16x8 __attribute__((ext_vector_type(8)));
typedef float    f32x4 __attribute__((ext_vector_type(4)));

union FragH  { uint4 q; f16x8 v; f16x2 h2[4]; _Float16 h[8]; };

// ---------------------------------------------------------------------------
// Pre-kernel 1: planes [N,P,C,H,W] f32  ->  planesT [N*P, H, W, C] fp16
__global__ void transpose_planes(const float* __restrict__ planes,
                                 unsigned short* __restrict__ planesT) {
    __shared__ float tile[CCH * 65];
    int b  = blockIdx.x;            // np*64 + y
    int np = b >> 6, y = b & 63;
    int t  = threadIdx.x;
    const float* src = planes + (size_t)np * CCH * HWDIM * HWDIM + (size_t)y * HWDIM;
    for (int i = t; i < CCH * HWDIM; i += 256) {
        int c = i >> 6, w = i & 63;
        tile[c * 65 + w] = src[(size_t)c * (HWDIM * HWDIM) + w];
    }
    __syncthreads();
    unsigned short* dst = planesT + ((size_t)np * HWDIM + y) * HWDIM * CCH;
    for (int i = t; i < CCH * HWDIM; i += 256) {
        int w = i / CCH, c = i - w * CCH;
        union { _Float16 h; unsigned short u; } cv;
        cv.h = (_Float16)tile[c * 65 + w];
        dst[i] = cv.u;
    }
}

// ---------------------------------------------------------------------------
// Pre-kernel 2: W1 (240x64, K zero-padded to 256), W2, W3 (64x64) in fp16
// MFMA B-fragment order:
//   elem((kb,nt,lane,j)) = W[kb*32 + 8*(lane>>4)+j][nt*16 + (lane&15)]
// wpack ushort layout: W1[0..16384) W2[16384..20480) W3[20480..24576)
__global__ void pack_weights(const float* __restrict__ W1,
                             const float* __restrict__ W2,
                             const float* __restrict__ W3,
                             unsigned short* __restrict__ wpack) {
    int e = blockIdx.x * 256 + threadIdx.x;   // 0..24575
    const float* W; int K; int q;
    if (e < 16384)      { W = W1; K = 240; q = e; }
    else if (e < 20480) { W = W2; K = 64;  q = e - 16384; }
    else                { W = W3; K = 64;  q = e - 20480; }
    int j  = q & 7;
    int l  = (q >> 3) & 63;
    int nt = (q >> 9) & 3;
    int kb = q >> 11;
    int k  = kb * 32 + ((l >> 4) << 3) + j;
    int nn = nt * 16 + (l & 15);
    float v = (k < K) ? W[k * HID + nn] : 0.0f;
    union { _Float16 h; unsigned short u; } cv;
    cv.h = (_Float16)v;
    wpack[e] = cv.u;
}

// ---------------------------------------------------------------------------
// Main fused kernel: 256 threads = 4 waves, 16 points per wave.
// LDS: W1 fragments 32 KB + H tiles 9 KB = 41 KB -> 3 blocks/CU.
__global__ __launch_bounds__(256, 3) void fused_kernel(
        const unsigned short* __restrict__ planesT,
        const float* __restrict__ coords,
        const unsigned short* __restrict__ wpack,
        const float* __restrict__ b1, const float* __restrict__ b2,
        const float* __restrict__ b3, const float* __restrict__ W4,
        const float* __restrict__ b4, float* __restrict__ out) {

    __shared__ __align__(16) unsigned short sW1[16384];      // 32 KiB (K=256 padded)
    __shared__ __align__(16) unsigned short sH[4 * 16 * 72]; // per-wave H tiles

    int t = threadIdx.x;
    {   // Stage W1 fragments: 2048 uint4 over 256 threads.
        const uint4* g = (const uint4*)wpack;
        uint4* s = (uint4*)sW1;
        #pragma unroll
        for (int i = 0; i < 8; ++i) s[t + i * 256] = g[t + i * 256];
    }

    int wave = t >> 6, lane = t & 63;
    int row  = lane & 15;       // point-in-wave (MFMA A row / C col)
    int kgrp = lane >> 4;       // K-group 0..3
    int ptbase = blockIdx.x * 64 + wave * 16;
    int mypt   = ptbase + row;
    int n      = mypt >> 19;    // MPTS = 2^19

    const float* cp = coords + (size_t)mypt * 3;
    float c0 = cp[0], c1 = cp[1], c2 = cp[2];

    // Per-plane bilinear params -> NAMED scalars; weights as packed f16 pairs.
    f16x2 w00_0, w01_0, w10_0, w11_0, w00_1, w01_1, w10_1, w11_1,
          w00_2, w01_2, w10_2, w11_2;
    int   o00_0, o01_0, o10_0, o11_0, o00_1, o01_1, o10_1, o11_1,
          o00_2, o01_2, o10_2, o11_2;
    {
        auto setup = [&](float gx, float gy, int pbase,
                         f16x2& w00, f16x2& w01, f16x2& w10, f16x2& w11,
                         int& o00, int& o01, int& o10, int& o11) {
            float fx = (gx + 1.0f) * 32.0f - 0.5f;
            float fy = (gy + 1.0f) * 32.0f - 0.5f;
            float xf = floorf(fx), yf = floorf(fy);
            float wx = fx - xf,    wy = fy - yf;
            int x0 = (int)xf, y0 = (int)yf, x1 = x0 + 1, y1 = y0 + 1;
            float vx0 = (x0 >= 0 && x0 < 64) ? 1.0f : 0.0f;
            float vx1 = (x1 >= 0 && x1 < 64) ? 1.0f : 0.0f;
            float vy0 = (y0 >= 0 && y0 < 64) ? 1.0f : 0.0f;
            float vy1 = (y1 >= 0 && y1 < 64) ? 1.0f : 0.0f;
            int cx0 = min(max(x0, 0), 63), cx1 = min(max(x1, 0), 63);
            int cy0 = min(max(y0, 0), 63), cy1 = min(max(y1, 0), 63);
            float f00 = (1.0f - wx) * (1.0f - wy) * vx0 * vy0;
            float f01 = wx * (1.0f - wy) * vx1 * vy0;
            float f10 = (1.0f - wx) * wy * vx0 * vy1;
            float f11 = wx * wy * vx1 * vy1;
            _Float16 h00 = (_Float16)f00, h01 = (_Float16)f01;
            _Float16 h10 = (_Float16)f10, h11 = (_Float16)f11;
            w00 = f16x2{h00, h00}; w01 = f16x2{h01, h01};
            w10 = f16x2{h10, h10}; w11 = f16x2{h11, h11};
            o00 = pbase + ((cy0 << 6) + cx0) * CCH;
            o01 = pbase + ((cy0 << 6) + cx1) * CCH;
            o10 = pbase + ((cy1 << 6) + cx0) * CCH;
            o11 = pbase + ((cy1 << 6) + cx1) * CCH;
        };
        int nb = n * 3 * (HWDIM * HWDIM * CCH);
        setup(c0, c1, nb,                           w00_0, w01_0, w10_0, w11_0,
                                                    o00_0, o01_0, o10_0, o11_0);
        setup(c0, c2, nb + HWDIM * HWDIM * CCH,     w00_1, w01_1, w10_1, w11_1,
                                                    o00_1, o01_1, o10_1, o11_1);
        setup(c2, c1, nb + 2 * HWDIM * HWDIM * CCH, w00_2, w01_2, w10_2, w11_2,
                                                    o00_2, o01_2, o10_2, o11_2);
    }

    // -------- Sample 8 A-fragments in packed fp16 --------------------------
    FragH afr[8];
    #pragma unroll
    for (int kk = 0; kk < 8; ++kk) {
        int k0 = kk * 32 + kgrp * 8;
        if (k0 >= 240) {                    // K padding 240..255
            afr[kk].q.x = afr[kk].q.y = afr[kk].q.z = afr[kk].q.w = 0u;
            continue;
        }
        bool g2 = (k0 >= 160);
        bool g1 = (k0 >= 80) && !g2;
        int c8 = k0 - (g2 ? 160 : (g1 ? 80 : 0));
        int o00 = g2 ? o00_2 : (g1 ? o00_1 : o00_0);
        int o01 = g2 ? o01_2 : (g1 ? o01_1 : o01_0);
        int o10 = g2 ? o10_2 : (g1 ? o10_1 : o10_0);
        int o11 = g2 ? o11_2 : (g1 ? o11_1 : o11_0);
        f16x2 a00 = g2 ? w00_2 : (g1 ? w00_1 : w00_0);
        f16x2 a01 = g2 ? w01_2 : (g1 ? w01_1 : w01_0);
        f16x2 a10 = g2 ? w10_2 : (g1 ? w10_1 : w10_0);
        f16x2 a11 = g2 ? w11_2 : (g1 ? w11_1 : w11_0);

        FragH u00, u01, u10, u11;
        u00.q = *(const uint4*)(planesT + o00 + c8);
        u01.q = *(const uint4*)(planesT + o01 + c8);
        u10.q = *(const uint4*)(planesT + o10 + c8);
        u11.q = *(const uint4*)(planesT + o11 + c8);
        #pragma unroll
        for (int j2 = 0; j2 < 4; ++j2) {
            f16x2 acc = u00.h2[j2] * a00;
            acc = acc + u01.h2[j2] * a01;     // v_pk_fma_f16 chain
            acc = acc + u10.h2[j2] * a10;
            acc = acc + u11.h2[j2] * a11;
            afr[kk].h2[j2] = acc;
        }
    }

    __syncthreads();   // W1 staged

    // -------- Layer 1: K=256(padded), N=64, B from LDS ---------------------
    f32x4 acc[4] = {{0,0,0,0},{0,0,0,0},{0,0,0,0},{0,0,0,0}};
    #pragma unroll
    for (int kk = 0; kk < 8; ++kk) {
        #pragma unroll
        for (int nt = 0; nt < 4; ++nt) {
            FragH bu;
            bu.q = *(const uint4*)(sW1 + (kk * 4 + nt) * 512 + lane * 8);
            acc[nt] = __builtin_amdgcn_mfma_f32_16x16x32_f16(afr[kk].v, bu.v, acc[nt], 0, 0, 0);
        }
    }

    unsigned short* hw = sH + wave * (16 * 72);
    _Float16* hwh = (_Float16*)hw;

    // Epilogue 1
    #pragma unroll
    for (int nt = 0; nt < 4; ++nt) {
        float bb = b1[nt * 16 + row];
        #pragma unroll
        for (int r = 0; r < 4; ++r) {
            float h = fmaxf(acc[nt][r] + bb, 0.0f);
            hwh[(kgrp * 4 + r) * 72 + nt * 16 + row] = (_Float16)h;
        }
    }
    __syncthreads();

    // -------- Layer 2: K=64, B fragments from global (L1-hot) --------------
    f32x4 acc2[4] = {{0,0,0,0},{0,0,0,0},{0,0,0,0},{0,0,0,0}};
    #pragma unroll
    for (int kk = 0; kk < 2; ++kk) {
        FragH au;
        au.q = *(const uint4*)(hw + row * 72 + kk * 32 + kgrp * 8);
        #pragma unroll
        for (int nt = 0; nt < 4; ++nt) {
            FragH bu;
            bu.q = *(const uint4*)(wpack + 16384 + (kk * 4 + nt) * 512 + lane * 8);
            acc2[nt] = __builtin_amdgcn_mfma_f32_16x16x32_f16(au.v, bu.v, acc2[nt], 0, 0, 0);
        }
    }
    __syncthreads();

    // Epilogue 2
    #pragma unroll
    for (int nt = 0; nt < 4; ++nt) {
        float bb = b2[nt * 16 + row];
        #pragma unroll
        for (int r = 0; r < 4; ++r) {
            float h = fmaxf(acc2[nt][r] + bb, 0.0f);
            hwh[(kgrp * 4 + r) * 72 + nt * 16 + row] = (_Float16)h;
        }
    }
    __syncthreads();

    // -------- Layer 3: K=64, B from global ---------------------------------
    f32x4 acc3[4] = {{0,0,0,0},{0,0,0,0},{0,0,0,0},{0,0,0,0}};
    #pragma unroll
    for (int kk = 0; kk < 2; ++kk) {
        FragH au;
        au.q = *(const uint4*)(hw + row * 72 + kk * 32 + kgrp * 8);
        #pragma unroll
        for (int nt = 0; nt < 4; ++nt) {
            FragH bu;
            bu.q = *(const uint4*)(wpack + 20480 + (kk * 4 + nt) * 512 + lane * 8);
            acc3[nt] = __builtin_amdgcn_mfma_f32_16x16x32_f16(au.v, bu.v, acc3[nt], 0, 0, 0);
        }
    }

    // -------- Layer 4: 64 -> 1, fp32 VALU + 16-lane reduce -----------------
    float part[4] = {0.f, 0.f, 0.f, 0.f};
    #pragma unroll
    for (int nt = 0; nt < 4; ++nt) {
        float bb  = b3[nt * 16 + row];
        float w4v = W4[nt * 16 + row];
        #pragma unroll
        for (int r = 0; r < 4; ++r) {
            float h = fmaxf(acc3[nt][r] + bb, 0.0f);
            part[r] += h * w4v;
        }
    }
    #pragma unroll
    for (int r = 0; r < 4; ++r) {
        #pragma unroll
        for (int off = 1; off < 16; off <<= 1)
            part[r] += __shfl_xor(part[r], off);
    }
    if (row == 0) {
        float bias4 = b4[0];
        float4 o;
        o.x = part[0] + bias4; o.y = part[1] + bias4;
        o.z = part[2] + bias4; o.w = part[3] + bias4;
        *(float4*)(out + ptbase + kgrp * 4) = o;   // points m = kgrp*4 + r
    }
}

// ---------------------------------------------------------------------------
extern "C" void kernel_launch(void* const* d_in, const int* in_sizes, int n_in,
                              void* d_out, int out_size, void* d_ws, size_t ws_size,
                              hipStream_t stream) {
    const float* planes = (const float*)d_in[0];
    const float* coords = (const float*)d_in[1];
    const float* W1 = (const float*)d_in[2];
    const float* b1 = (const float*)d_in[3];
    const float* W2 = (const float*)d_in[4];
    const float* b2 = (const float*)d_in[5];
    const float* W3 = (const float*)d_in[6];
    const float* b3 = (const float*)d_in[7];
    const float* W4 = (const float*)d_in[8];
    const float* b4 = (const float*)d_in[9];
    float* out = (float*)d_out;

    // Workspace: planesT fp16 (3,932,160 B) | wpack fp16 (49,152 B)
    unsigned short* planesT = (unsigned short*)d_ws;
    unsigned short* wpack   = (unsigned short*)((char*)d_ws + 3932160);

    hipLaunchKernelGGL(transpose_planes, dim3(NB * 3 * HWDIM), dim3(256), 0, stream,
                       planes, planesT);
    hipLaunchKernelGGL(pack_weights, dim3(96), dim3(256), 0, stream,
                       W1, W2, W3, wpack);

    int nblocks = (NB * MPTS) / 64;   // 16384
    hipLaunchKernelGGL(fused_kernel, dim3(nblocks), dim3(256), 0, stream,
                       planesT, coords, wpack, b1, b2, b3, W4, b4, out);
}

// Round 5
// 112.349 us; speedup vs baseline: 3.2826x; 2.0264x over previous
//
#include <hip/hip_runtime.h>
#include <hip/hip_bf16.h>
#include <stdint.h>

// Problem constants
#define MPTS  524288      // M per batch
#define NB    2           // N
#define CCH   80          // C
#define HWDIM 64          // H = W
#define HID   64

typedef _Float16 f16x2 __attribute__((ext_vector_type(2)));
typedef _Float16 f16x8 __attribute__((ext_vector_type(8)));
typedef float    f32x4 __attribute__((ext_vector_type(4)));

union FragH { uint4 q; f16x8 v; f16x2 h2[4]; _Float16 h[8]; };

// ---------------------------------------------------------------------------
// Pre-kernel 1: planesW[np][y][x][64] fp16 = texel(80ch fp32) @ W1_p(80x64).
// Texel stride 64 el = 128 B (two 64-B lines, always aligned).
// Grid: 6*64 blocks (np, y), 256 threads.
__global__ void precompute_planesW(const float* __restrict__ planes,
                                   const float* __restrict__ W1,
                                   unsigned short* __restrict__ planesW) {
    __shared__ float tA[CCH * 64];   // [c][px]
    __shared__ float tW[CCH * 64];   // [c][nn]
    int b  = blockIdx.x;
    int np = b >> 6, y = b & 63;
    int p  = np % 3;
    int t  = threadIdx.x;
    for (int i = t; i < CCH * 64; i += 256) {
        int c = i >> 6, x = i & 63;
        tA[i] = planes[((size_t)np * CCH + c) * 4096 + y * 64 + x];
        tW[i] = W1[(p * CCH + c) * HID + x];     // x plays the role of nn
    }
    __syncthreads();
    int px = t >> 2;               // 0..63
    int n0 = (t & 3) * 16;         // output-dim base
    float acc[16];
    #pragma unroll
    for (int i = 0; i < 16; ++i) acc[i] = 0.0f;
    for (int c = 0; c < CCH; ++c) {
        float a = tA[c * 64 + px];
        #pragma unroll
        for (int i = 0; i < 16; ++i) acc[i] += a * tW[c * 64 + n0 + i];
    }
    unsigned short* dst = planesW + (((size_t)np * 4096) + y * 64 + px) * HID + n0;
    #pragma unroll
    for (int i = 0; i < 16; ++i) {
        union { _Float16 h; unsigned short u; } cv;
        cv.h = (_Float16)acc[i];
        dst[i] = cv.u;
    }
}

// ---------------------------------------------------------------------------
// Pre-kernel 2: W2, W3 (64x64) in fp16 MFMA B-fragment order (proven layout):
//   elem((kb,nt,lane,j)) = W[kb*32 + 8*(lane>>4)+j][nt*16 + (lane&15)]
// wpack ushort layout: W2[0..4096) W3[4096..8192)
__global__ void pack_weights23(const float* __restrict__ W2,
                               const float* __restrict__ W3,
                               unsigned short* __restrict__ wpack) {
    int e = blockIdx.x * 256 + threadIdx.x;   // 0..8191
    const float* W = (e < 4096) ? W2 : W3;
    int q  = e & 4095;
    int j  = q & 7;
    int l  = (q >> 3) & 63;
    int nt = (q >> 9) & 3;
    int kb = q >> 11;
    int k  = kb * 32 + ((l >> 4) << 3) + j;
    int nn = nt * 16 + (l & 15);
    union { _Float16 h; unsigned short u; } cv;
    cv.h = (_Float16)W[k * HID + nn];
    wpack[e] = cv.u;
}

// ---------------------------------------------------------------------------
// Main fused kernel: 256 threads = 4 waves, 16 points per wave.
// LDS: per-wave H tiles only (9 KB). W2/W3 fragments from global (L1-hot).
__global__ __launch_bounds__(256, 5) void fused_kernel(
        const unsigned short* __restrict__ planesW,
        const float* __restrict__ coords,
        const unsigned short* __restrict__ wpack,
        const float* __restrict__ b1, const float* __restrict__ b2,
        const float* __restrict__ b3, const float* __restrict__ W4,
        const float* __restrict__ b4, float* __restrict__ out) {

    __shared__ __align__(16) unsigned short sH[4 * 16 * 72]; // per-wave H tiles

    int t    = threadIdx.x;
    int wave = t >> 6, lane = t & 63;
    int ptbase = blockIdx.x * 64 + wave * 16;

    unsigned short* hw = sH + wave * (16 * 72);
    _Float16* hwh = (_Float16*)hw;

    // ---------- Phase 1: gather + layer 1 (VALU) ---------------------------
    // Lane roles: sub = lane&7 (8-dim octet), ptg = lane>>3 (point group).
    // Two rounds cover 16 points; 8 consecutive lanes read 8 consecutive
    // 16-B chunks of each 128-B texel -> perfect line merge.
    {
        int sub = lane & 7;
        int ptg = lane >> 3;

        // b1 slice for this lane (dims sub*8 .. +8), hoisted across rounds.
        float b1f[8];
        {
            const float4* bp = (const float4*)(b1 + sub * 8);
            float4 v0 = bp[0], v1 = bp[1];
            b1f[0] = v0.x; b1f[1] = v0.y; b1f[2] = v0.z; b1f[3] = v0.w;
            b1f[4] = v1.x; b1f[5] = v1.y; b1f[6] = v1.z; b1f[7] = v1.w;
        }

        #pragma unroll
        for (int r = 0; r < 2; ++r) {
            int pt   = r * 8 + ptg;
            int mypt = ptbase + pt;
            int n    = mypt >> 19;             // MPTS = 2^19

            const float* cp = coords + (size_t)mypt * 3;
            float c0 = cp[0], c1 = cp[1], c2 = cp[2];

            float wt[3][4];
            int   off[3][4];
            #pragma unroll
            for (int p = 0; p < 3; ++p) {
                float gx = (p == 2) ? c2 : c0;     // p0:(x,y) p1:(x,z) p2:(z,y)
                float gy = (p == 1) ? c2 : c1;
                float fx = (gx + 1.0f) * 32.0f - 0.5f;
                float fy = (gy + 1.0f) * 32.0f - 0.5f;
                float xf = floorf(fx), yf = floorf(fy);
                float wx = fx - xf,    wy = fy - yf;
                int x0 = (int)xf, y0 = (int)yf, x1 = x0 + 1, y1 = y0 + 1;
                float vx0 = (x0 >= 0 && x0 < 64) ? 1.0f : 0.0f;
                float vx1 = (x1 >= 0 && x1 < 64) ? 1.0f : 0.0f;
                float vy0 = (y0 >= 0 && y0 < 64) ? 1.0f : 0.0f;
                float vy1 = (y1 >= 0 && y1 < 64) ? 1.0f : 0.0f;
                int cx0 = min(max(x0, 0), 63), cx1 = min(max(x1, 0), 63);
                int cy0 = min(max(y0, 0), 63), cy1 = min(max(y1, 0), 63);
                wt[p][0] = (1.0f - wx) * (1.0f - wy) * vx0 * vy0;
                wt[p][1] = wx * (1.0f - wy) * vx1 * vy0;
                wt[p][2] = (1.0f - wx) * wy * vx0 * vy1;
                wt[p][3] = wx * wy * vx1 * vy1;
                int base = (n * 3 + p) * 4096;
                off[p][0] = (base + (cy0 << 6) + cx0) * HID;
                off[p][1] = (base + (cy0 << 6) + cx1) * HID;
                off[p][2] = (base + (cy1 << 6) + cx0) * HID;
                off[p][3] = (base + (cy1 << 6) + cx1) * HID;
            }

            float acc8[8];
            #pragma unroll
            for (int j = 0; j < 8; ++j) acc8[j] = b1f[j];
            #pragma unroll
            for (int p = 0; p < 3; ++p) {
                #pragma unroll
                for (int c = 0; c < 4; ++c) {
                    FragH u;
                    u.q = *(const uint4*)(planesW + off[p][c] + sub * 8);
                    float wgt = wt[p][c];
                    #pragma unroll
                    for (int j = 0; j < 8; ++j)
                        acc8[j] += wgt * (float)u.h[j];   // v_fma_mix_f32
                }
            }
            // ReLU + fp16, write H row (16-B ds_write).
            FragH hv;
            #pragma unroll
            for (int j = 0; j < 8; ++j)
                hv.h[j] = (_Float16)fmaxf(acc8[j], 0.0f);
            *(uint4*)(hwh + pt * 72 + sub * 8) = hv.q;
        }
    }
    __syncthreads();

    // ---------- Layer 2: K=64, A from LDS, B from global (proven) ----------
    int row  = lane & 15;
    int kgrp = lane >> 4;
    f32x4 acc2[4] = {{0,0,0,0},{0,0,0,0},{0,0,0,0},{0,0,0,0}};
    #pragma unroll
    for (int kk = 0; kk < 2; ++kk) {
        FragH au;
        au.q = *(const uint4*)(hw + row * 72 + kk * 32 + kgrp * 8);
        #pragma unroll
        for (int nt = 0; nt < 4; ++nt) {
            FragH bu;
            bu.q = *(const uint4*)(wpack + (kk * 4 + nt) * 512 + lane * 8);
            acc2[nt] = __builtin_amdgcn_mfma_f32_16x16x32_f16(au.v, bu.v, acc2[nt], 0, 0, 0);
        }
    }
    __syncthreads();

    // Epilogue 2
    #pragma unroll
    for (int nt = 0; nt < 4; ++nt) {
        float bb = b2[nt * 16 + row];
        #pragma unroll
        for (int r = 0; r < 4; ++r) {
            float h = fmaxf(acc2[nt][r] + bb, 0.0f);
            hwh[(kgrp * 4 + r) * 72 + nt * 16 + row] = (_Float16)h;
        }
    }
    __syncthreads();

    // ---------- Layer 3: K=64, B from global --------------------------------
    f32x4 acc3[4] = {{0,0,0,0},{0,0,0,0},{0,0,0,0},{0,0,0,0}};
    #pragma unroll
    for (int kk = 0; kk < 2; ++kk) {
        FragH au;
        au.q = *(const uint4*)(hw + row * 72 + kk * 32 + kgrp * 8);
        #pragma unroll
        for (int nt = 0; nt < 4; ++nt) {
            FragH bu;
            bu.q = *(const uint4*)(wpack + 4096 + (kk * 4 + nt) * 512 + lane * 8);
            acc3[nt] = __builtin_amdgcn_mfma_f32_16x16x32_f16(au.v, bu.v, acc3[nt], 0, 0, 0);
        }
    }

    // ---------- Layer 4: 64 -> 1, fp32 VALU + 16-lane reduce ----------------
    float part[4] = {0.f, 0.f, 0.f, 0.f};
    #pragma unroll
    for (int nt = 0; nt < 4; ++nt) {
        float bb  = b3[nt * 16 + row];
        float w4v = W4[nt * 16 + row];
        #pragma unroll
        for (int r = 0; r < 4; ++r) {
            float h = fmaxf(acc3[nt][r] + bb, 0.0f);
            part[r] += h * w4v;
        }
    }
    #pragma unroll
    for (int r = 0; r < 4; ++r) {
        #pragma unroll
        for (int off = 1; off < 16; off <<= 1)
            part[r] += __shfl_xor(part[r], off);
    }
    if (row == 0) {
        float bias4 = b4[0];
        float4 o;
        o.x = part[0] + bias4; o.y = part[1] + bias4;
        o.z = part[2] + bias4; o.w = part[3] + bias4;
        *(float4*)(out + ptbase + kgrp * 4) = o;   // points m = kgrp*4 + r
    }
}

// ---------------------------------------------------------------------------
extern "C" void kernel_launch(void* const* d_in, const int* in_sizes, int n_in,
                              void* d_out, int out_size, void* d_ws, size_t ws_size,
                              hipStream_t stream) {
    const float* planes = (const float*)d_in[0];
    const float* coords = (const float*)d_in[1];
    const float* W1 = (const float*)d_in[2];
    const float* b1 = (const float*)d_in[3];
    const float* W2 = (const float*)d_in[4];
    const float* b2 = (const float*)d_in[5];
    const float* W3 = (const float*)d_in[6];
    const float* b3 = (const float*)d_in[7];
    const float* W4 = (const float*)d_in[8];
    const float* b4 = (const float*)d_in[9];
    float* out = (float*)d_out;

    // Workspace: planesW fp16 (3,145,728 B) | wpack fp16 (16,384 B)
    unsigned short* planesW = (unsigned short*)d_ws;
    unsigned short* wpack   = (unsigned short*)((char*)d_ws + 3145728);

    hipLaunchKernelGGL(precompute_planesW, dim3(NB * 3 * HWDIM), dim3(256), 0, stream,
                       planes, W1, planesW);
    hipLaunchKernelGGL(pack_weights23, dim3(32), dim3(256), 0, stream,
                       W2, W3, wpack);

    int nblocks = (NB * MPTS) / 64;   // 16384
    hipLaunchKernelGGL(fused_kernel, dim3(nblocks), dim3(256), 0, stream,
                       planesW, coords, wpack, b1, b2, b3, W4, b4, out);
}